// Round 1
// baseline (2066.426 us; speedup 1.0000x reference)
//
#include <hip/hip_runtime.h>
#include <math.h>

// HyenaFilter: y = irfft(rfft(x,2L) * rfft(k,2L))[..., :L] + x*bias
// L=8192, D_MODEL=768, BATCH=8. Filter k built from tiny sinusoidal MLP + decay.
//
// Strategy: per-row fused FFT conv in LDS. 16384-pt rfft of an L-padded real
// row == one 8192-pt complex FFT (pack even/odd) + unpack. Inverse likewise.
// Radix-2 in-place DIT (bit-reversed load) forward, DIF (bit-reversed output)
// inverse via the re/im swap trick. 64 KB LDS/block.

#define LSEQ 8192
#define HALF 4096
#define NCH 768
#define NBATCH 8
#define NT 512

// ws layout (float offsets)
#define OFF_TW8R  0         // 4096: cos(-2pi k/8192)
#define OFF_TW8I  4096      // 4096: sin(-2pi k/8192)
#define OFF_TW16R 8192      // 4097: cos(-2pi k/16384)
#define OFF_TW16I 12320     // 4097
#define OFF_H     16448     // 8192*16 MLP features
#define OFF_KF    147520    // 768*8193*2 filter spectra (float2)

__device__ __forceinline__ int rev13(int n) { return (int)(__brev((unsigned)n) >> 19); }

// In-place radix-2 DIT. Input bit-reversed, output natural order.
__device__ void fft_dit(float* re, float* im, const float* twr, const float* twi) {
    const int tid = threadIdx.x;
    for (int s = 1; s <= 13; ++s) {
        const int half = 1 << (s - 1);
        const int twsh = 13 - s;
        for (int i = tid; i < LSEQ / 2; i += NT) {
            const int j = i & (half - 1);
            const int pos = ((i >> (s - 1)) << s) + j;
            const int ti = j << twsh;
            const float wr = twr[ti], wi = twi[ti];
            const float ur = re[pos], ui = im[pos];
            const float vr = re[pos + half], vi = im[pos + half];
            const float tr = vr * wr - vi * wi;
            const float t2 = vr * wi + vi * wr;
            re[pos] = ur + tr;        im[pos] = ui + t2;
            re[pos + half] = ur - tr; im[pos + half] = ui - t2;
        }
        __syncthreads();
    }
}

// In-place radix-2 DIF. Input natural order, output bit-reversed.
__device__ void fft_dif(float* re, float* im, const float* twr, const float* twi) {
    const int tid = threadIdx.x;
    for (int s = 13; s >= 1; --s) {
        const int half = 1 << (s - 1);
        const int twsh = 13 - s;
        for (int i = tid; i < LSEQ / 2; i += NT) {
            const int j = i & (half - 1);
            const int pos = ((i >> (s - 1)) << s) + j;
            const int ti = j << twsh;
            const float wr = twr[ti], wi = twi[ti];
            const float ur = re[pos], ui = im[pos];
            const float vr = re[pos + half], vi = im[pos + half];
            re[pos] = ur + vr; im[pos] = ui + vi;
            const float dr = ur - vr, di = ui - vi;
            re[pos + half] = dr * wr - di * wi;
            im[pos + half] = dr * wi + di * wr;
        }
        __syncthreads();
    }
}

__global__ void k_init(float* __restrict__ ws) {
    const int k = blockIdx.x * blockDim.x + threadIdx.x;
    if (k < 4096) {
        const double a = -2.0 * 3.14159265358979323846 * (double)k / 8192.0;
        ws[OFF_TW8R + k] = (float)cos(a);
        ws[OFF_TW8I + k] = (float)sin(a);
    }
    if (k <= 4096) {
        const double a = -2.0 * 3.14159265358979323846 * (double)k / 16384.0;
        ws[OFF_TW16R + k] = (float)cos(a);
        ws[OFF_TW16I + k] = (float)sin(a);
    }
}

__global__ void k_mlp(const float* __restrict__ z, const float* __restrict__ freq,
                      const float* __restrict__ W0, const float* __restrict__ b0,
                      const float* __restrict__ W1, const float* __restrict__ b1,
                      const float* __restrict__ W2, const float* __restrict__ b2,
                      float* __restrict__ H) {
    const int j = blockIdx.x * blockDim.x + threadIdx.x;
    if (j >= LSEQ) return;
    const float z0 = z[j * 3 + 0], z1 = z[j * 3 + 1], z2 = z[j * 3 + 2];
    float h[16], g[16];
#pragma unroll
    for (int m = 0; m < 16; ++m)
        h[m] = sinf(freq[m] * (z0 * W0[m] + z1 * W0[16 + m] + z2 * W0[32 + m] + b0[m]));
#pragma unroll
    for (int m = 0; m < 16; ++m) {
        float a = b1[m];
#pragma unroll
        for (int p = 0; p < 16; ++p) a += h[p] * W1[p * 16 + m];
        g[m] = sinf(freq[m] * a);
    }
#pragma unroll
    for (int m = 0; m < 16; ++m) {
        float a = b2[m];
#pragma unroll
        for (int p = 0; p < 16; ++p) a += g[p] * W2[p * 16 + m];
        h[m] = sinf(freq[m] * a);
    }
#pragma unroll
    for (int m = 0; m < 16; ++m) H[j * 16 + m] = h[m];
}

// Per-channel: build k[c,:], pack, FFT, unpack to true 16384-pt spectrum bins 0..8192.
__global__ __launch_bounds__(NT) void k_filter(const float* __restrict__ H, const float* __restrict__ t,
                                               const float* __restrict__ deltas, const float* __restrict__ W3,
                                               const float* __restrict__ b3, const float* __restrict__ ws,
                                               float* __restrict__ KfF) {
    __shared__ float sRe[LSEQ];
    __shared__ float sIm[LSEQ];
    const int c = blockIdx.x;
    const int tid = threadIdx.x;
    const float* twr = ws + OFF_TW8R;
    const float* twi = ws + OFF_TW8I;
    const float* t16r = ws + OFF_TW16R;
    const float* t16i = ws + OFF_TW16I;
    float w3[16];
#pragma unroll
    for (int m = 0; m < 16; ++m) w3[m] = W3[m * NCH + c];
    const float b3c = b3[c];
    const float ad = fabsf(deltas[c]);
    for (int n = tid; n < LSEQ; n += NT) {
        float a = 0.f, b = 0.f;
        if (n < HALF) {
            const int j0 = 2 * n, j1 = 2 * n + 1;
            float s0 = b3c, s1 = b3c;
#pragma unroll
            for (int m = 0; m < 16; ++m) { s0 += H[j0 * 16 + m] * w3[m]; s1 += H[j1 * 16 + m] * w3[m]; }
            a = s0 * expf(-t[j0] * ad);
            b = s1 * expf(-t[j1] * ad);
        }
        const int r = rev13(n);
        sRe[r] = a; sIm[r] = b;
    }
    __syncthreads();
    fft_dit(sRe, sIm, twr, twi);
    float2* kf = (float2*)KfF + (size_t)c * 8193;
    for (int k = tid; k <= HALF; k += NT) {
        if (k == 0) {
            const float v0r = sRe[0], v0i = sIm[0];
            kf[0] = make_float2(v0r + v0i, 0.f);
            kf[8192] = make_float2(v0r - v0i, 0.f);
        } else if (k == HALF) {
            kf[HALF] = make_float2(sRe[HALF], -sIm[HALF]);
        } else {
            const float var = sRe[k], vai = sIm[k];
            const float vbr = sRe[LSEQ - k], vbi = sIm[LSEQ - k];
            const float Er = 0.5f * (var + vbr), Ei = 0.5f * (vai - vbi);
            const float Or = 0.5f * (vai + vbi), Oi = 0.5f * (vbr - var);
            const float wr = t16r[k], wi = t16i[k];
            const float WOr = Or * wr - Oi * wi, WOi = Or * wi + Oi * wr;
            kf[k]        = make_float2(Er + WOr, Ei + WOi);
            kf[LSEQ - k] = make_float2(Er - WOr, -(Ei - WOi));
        }
    }
}

// Per-row: pack x, FFT, unpack*Kf*repack (fused), inverse FFT, +x*bias, store.
__global__ __launch_bounds__(NT) void k_main(const float* __restrict__ x, const float* __restrict__ ws,
                                             const float* __restrict__ KfF, const float* __restrict__ bias,
                                             float* __restrict__ out) {
    __shared__ float sRe[LSEQ];
    __shared__ float sIm[LSEQ];
    const int row = blockIdx.x;
    const int c = row % NCH;
    const int tid = threadIdx.x;
    const float* twr = ws + OFF_TW8R;
    const float* twi = ws + OFF_TW8I;
    const float* t16r = ws + OFF_TW16R;
    const float* t16i = ws + OFF_TW16I;
    const float2* xrow = (const float2*)(x + (size_t)row * LSEQ);
    const float2* kf = (const float2*)KfF + (size_t)c * 8193;

    for (int n = tid; n < LSEQ; n += NT) {
        float a = 0.f, b = 0.f;
        if (n < HALF) { const float2 v = xrow[n]; a = v.x; b = v.y; }
        const int r = rev13(n);
        sRe[r] = a; sIm[r] = b;
    }
    __syncthreads();
    fft_dit(sRe, sIm, twr, twi);

    // unpack to U[k] (true 16384-pt bins), multiply by K, repack to inverse-input spectrum
    for (int k = tid; k <= HALF; k += NT) {
        if (k == 0) {
            const float v0r = sRe[0], v0i = sIm[0];
            const float U0 = v0r + v0i, UL = v0r - v0i;   // real bins 0 and 8192
            const float P0 = U0 * kf[0].x;
            const float PL = UL * kf[8192].x;
            sRe[0] = 0.5f * (P0 + PL);
            sIm[0] = 0.5f * (P0 - PL);
        } else if (k == HALF) {
            const float Ur = sRe[HALF], Ui = -sIm[HALF];  // U = conj(V)
            const float2 Kv = kf[HALF];
            const float Pr = Ur * Kv.x - Ui * Kv.y;
            const float Pi = Ur * Kv.y + Ui * Kv.x;
            sRe[HALF] = Pr; sIm[HALF] = -Pi;              // v' = conj(P)
        } else {
            const float var = sRe[k], vai = sIm[k];
            const float vbr = sRe[LSEQ - k], vbi = sIm[LSEQ - k];
            const float Er = 0.5f * (var + vbr), Ei = 0.5f * (vai - vbi);
            const float Or = 0.5f * (vai + vbi), Oi = 0.5f * (vbr - var);
            const float wr = t16r[k], wi = t16i[k];
            const float WOr = Or * wr - Oi * wi, WOi = Or * wi + Oi * wr;
            const float U1r = Er + WOr, U1i = Ei + WOi;        // U[k]
            const float U2r = Er - WOr, U2i = -(Ei - WOi);     // U[L-k]
            const float2 K1 = kf[k], K2 = kf[LSEQ - k];
            const float P1r = U1r * K1.x - U1i * K1.y, P1i = U1r * K1.y + U1i * K1.x;
            const float P2r = U2r * K2.x - U2i * K2.y, P2i = U2r * K2.y + U2i * K2.x;
            const float Epr = 0.5f * (P1r + P2r), Epi = 0.5f * (P1i - P2i);
            const float Qr = P1r - P2r, Qi = P1i + P2i;
            const float Opr = 0.5f * (Qr * wr + Qi * wi);      // O' = 0.5*Q*conj(W)
            const float Opi = 0.5f * (Qi * wr - Qr * wi);
            sRe[k] = Epr - Opi;        sIm[k] = Epi + Opr;         // E' + iO'
            sRe[LSEQ - k] = Epr + Opi; sIm[LSEQ - k] = Opr - Epi;  // conj(E') + i conj(O')
        }
    }
    __syncthreads();

    // inverse: IDFT = swap(DFT(swap(.)))/L ; DIF leaves bins bit-reversed
    fft_dif(sIm, sRe, twr, twi);

    const float bc = bias[c];
    float2* orow = (float2*)(out + (size_t)row * LSEQ);
    const float inv = 1.0f / 8192.0f;
    for (int n = tid; n < HALF; n += NT) {
        const int r = rev13(n);
        const float2 xv = xrow[n];
        orow[n] = make_float2(sRe[r] * inv + xv.x * bc, sIm[r] * inv + xv.y * bc);
    }
}

extern "C" void kernel_launch(void* const* d_in, const int* in_sizes, int n_in,
                              void* d_out, int out_size, void* d_ws, size_t ws_size,
                              hipStream_t stream) {
    const float* x      = (const float*)d_in[0];
    // d_in[1] = L (int scalar) — compile-time constant here
    const float* z      = (const float*)d_in[2];
    const float* t      = (const float*)d_in[3];
    const float* deltas = (const float*)d_in[4];
    const float* freq   = (const float*)d_in[5];
    const float* W0     = (const float*)d_in[6];
    const float* b0     = (const float*)d_in[7];
    const float* W1     = (const float*)d_in[8];
    const float* b1     = (const float*)d_in[9];
    const float* W2     = (const float*)d_in[10];
    const float* b2     = (const float*)d_in[11];
    const float* W3     = (const float*)d_in[12];
    const float* b3     = (const float*)d_in[13];
    const float* bias   = (const float*)d_in[14];
    float* out = (float*)d_out;
    float* ws  = (float*)d_ws;
    float* H   = ws + OFF_H;
    float* Kf  = ws + OFF_KF;

    hipLaunchKernelGGL(k_init, dim3(17), dim3(256), 0, stream, ws);
    hipLaunchKernelGGL(k_mlp, dim3(32), dim3(256), 0, stream, z, freq, W0, b0, W1, b1, W2, b2, H);
    hipLaunchKernelGGL(k_filter, dim3(NCH), dim3(NT), 0, stream, H, t, deltas, W3, b3, ws, Kf);
    hipLaunchKernelGGL(k_main, dim3(NBATCH * NCH), dim3(NT), 0, stream, x, ws, Kf, bias, out);
}

// Round 2
// 725.511 us; speedup vs baseline: 2.8482x; 2.8482x over previous
//
#include <hip/hip_runtime.h>
#include <math.h>

// HyenaFilter: y = irfft(rfft(x,2L) * rfft(k,2L))[..., :L] + x*bias
// Register-blocked mixed-radix [16,16,16,2] FFT, digit-reversed spectral
// domain multiply, XOR-swizzled LDS (no bank conflicts), twiddle recurrence.

#define LSEQ 8192
#define NCH 768
#define NBATCH 8
#define NT 512

// ws layout (float offsets)
#define OFF_TW   0        // 512 float2 : W_8192^j, j<512
#define OFF_TW16 1024     // 4097 float2: W_16384^k, k<=4096
#define OFF_H    10240    // 16 x 8192 floats (transposed MLP features)
#define OFF_KF   141312   // 768 x 4096 float4 (S~, D~ per bin pair)

__device__ __forceinline__ float2 cadd(float2 a, float2 b){ return make_float2(a.x+b.x, a.y+b.y); }
__device__ __forceinline__ float2 csub(float2 a, float2 b){ return make_float2(a.x-b.x, a.y-b.y); }
__device__ __forceinline__ float2 cmul(float2 a, float2 b){ return make_float2(a.x*b.x - a.y*b.y, a.x*b.y + a.y*b.x); }
__device__ __forceinline__ float2 mni(float2 a){ return make_float2(a.y, -a.x); }  // * -i

// XOR swizzle on float2 index: breaks all power-of-2 stride conflicts
__device__ __forceinline__ int IDX(int i){ return i ^ (((i>>4) ^ (i>>8)) & 15); }

// digit-reversal: bin k -> slot p after DIF passes [16(512),16(32),16(2),2]
__device__ __forceinline__ int drev(int k){
    return ((k & 15) << 9) | (((k >> 4) & 15) << 5) | (((k >> 8) & 15) << 1) | (k >> 12);
}

#define C1 0.923879532511286756f
#define S1 0.382683432365089772f
#define R2 0.707106781186547524f

// natural-in DFT-16 on registers; output: bin m lives in q[rv[m]]
__device__ __forceinline__ void dft16(float2 q[16]) {
#pragma unroll
    for (int j = 0; j < 8; ++j) { float2 u=q[j], v=q[j+8]; q[j]=cadd(u,v); q[j+8]=csub(u,v); }
    q[9]  = cmul(q[9],  make_float2( C1,-S1));
    q[10] = cmul(q[10], make_float2( R2,-R2));
    q[11] = cmul(q[11], make_float2( S1,-C1));
    q[12] = mni(q[12]);
    q[13] = cmul(q[13], make_float2(-S1,-C1));
    q[14] = cmul(q[14], make_float2(-R2,-R2));
    q[15] = cmul(q[15], make_float2(-C1,-S1));
#pragma unroll
    for (int b = 0; b < 16; b += 8) {
#pragma unroll
        for (int j = 0; j < 4; ++j) { float2 u=q[b+j], v=q[b+j+4]; q[b+j]=cadd(u,v); q[b+j+4]=csub(u,v); }
        q[b+5] = cmul(q[b+5], make_float2( R2,-R2));
        q[b+6] = mni(q[b+6]);
        q[b+7] = cmul(q[b+7], make_float2(-R2,-R2));
    }
#pragma unroll
    for (int b = 0; b < 16; b += 4) {
        float2 u0=q[b], v0=q[b+2], u1=q[b+1], v1=q[b+3];
        q[b]=cadd(u0,v0); q[b+2]=csub(u0,v0);
        q[b+1]=cadd(u1,v1); q[b+3]=mni(csub(u1,v1));
    }
#pragma unroll
    for (int b = 0; b < 16; b += 2) { float2 u=q[b], v=q[b+1]; q[b]=cadd(u,v); q[b+1]=csub(u,v); }
}

// One radix-16 pass. DIT=false: DFT16 then y[m]*=W_M^{mp} (DIF, forward).
// DIT=true: in[r]*=W_M^{rp} then DFT16 (transposed pass, for the inverse net).
template<bool DIT>
__device__ __forceinline__ void r16_pass(float2* lds, int base, int p, int L,
                                         int twstride, const float2* __restrict__ tw) {
    const int rv[16] = {0,8,4,12,2,10,6,14,1,9,5,13,3,11,7,15};
    float2 q[16];
#pragma unroll
    for (int r = 0; r < 16; ++r) q[r] = lds[IDX(base + p + r*L)];
    float2 w = tw[p * twstride];
    if (DIT) {
        float2 wm = w;
#pragma unroll
        for (int r = 1; r < 16; ++r) { q[r] = cmul(q[r], wm); if (r < 15) wm = cmul(wm, w); }
    }
    dft16(q);
    if (!DIT) {
        float2 wm = w;
#pragma unroll
        for (int m = 1; m < 16; ++m) { q[rv[m]] = cmul(q[rv[m]], wm); if (m < 15) wm = cmul(wm, w); }
    }
#pragma unroll
    for (int m = 0; m < 16; ++m) lds[IDX(base + p + m*L)] = q[rv[m]];
}

__device__ __forceinline__ void r2_pass(float2* lds, int tid) {
#pragma unroll
    for (int j = 0; j < 8; ++j) {
        int i = tid + NT*j;
        int pa = IDX(2*i), pb = IDX(2*i+1);
        float2 u = lds[pa], v = lds[pb];
        lds[pa] = cadd(u,v); lds[pb] = csub(u,v);
    }
}

__device__ __forceinline__ void fwd_fft(float2* lds, int tid, const float2* __restrict__ tw) {
    r16_pass<false>(lds, 0, tid, 512, 1, tw);                 __syncthreads();
    r16_pass<false>(lds, (tid>>5)<<9, tid&31, 32, 16, tw);    __syncthreads();
    r16_pass<false>(lds, (tid>>1)<<5, tid&1, 2, 256, tw);     __syncthreads();
    r2_pass(lds, tid);                                        __syncthreads();
}

__device__ __forceinline__ void inv_fft(float2* lds, int tid, const float2* __restrict__ tw) {
    r2_pass(lds, tid);                                        __syncthreads();
    r16_pass<true>(lds, (tid>>1)<<5, tid&1, 2, 256, tw);      __syncthreads();
    r16_pass<true>(lds, (tid>>5)<<9, tid&31, 32, 16, tw);     __syncthreads();
    r16_pass<true>(lds, 0, tid, 512, 1, tw);                  __syncthreads();
}

__global__ void k_init(float* __restrict__ ws) {
    const int k = blockIdx.x * blockDim.x + threadIdx.x;
    if (k < 512) {
        const double a = -2.0 * 3.14159265358979323846 * (double)k / 8192.0;
        ws[OFF_TW + 2*k] = (float)cos(a); ws[OFF_TW + 2*k+1] = (float)sin(a);
    }
    if (k <= 4096) {
        const double a = -2.0 * 3.14159265358979323846 * (double)k / 16384.0;
        ws[OFF_TW16 + 2*k] = (float)cos(a); ws[OFF_TW16 + 2*k+1] = (float)sin(a);
    }
}

__global__ void k_mlp(const float* __restrict__ z, const float* __restrict__ freq,
                      const float* __restrict__ W0, const float* __restrict__ b0,
                      const float* __restrict__ W1, const float* __restrict__ b1,
                      const float* __restrict__ W2, const float* __restrict__ b2,
                      float* __restrict__ H) {
    const int j = blockIdx.x * blockDim.x + threadIdx.x;
    if (j >= LSEQ) return;
    const float z0 = z[j*3+0], z1 = z[j*3+1], z2 = z[j*3+2];
    float h[16], g[16];
#pragma unroll
    for (int m = 0; m < 16; ++m)
        h[m] = sinf(freq[m] * (z0*W0[m] + z1*W0[16+m] + z2*W0[32+m] + b0[m]));
#pragma unroll
    for (int m = 0; m < 16; ++m) {
        float a = b1[m];
#pragma unroll
        for (int p = 0; p < 16; ++p) a += h[p] * W1[p*16+m];
        g[m] = sinf(freq[m] * a);
    }
#pragma unroll
    for (int m = 0; m < 16; ++m) {
        float a = b2[m];
#pragma unroll
        for (int p = 0; p < 16; ++p) a += g[p] * W2[p*16+m];
        h[m] = sinf(freq[m] * a);
    }
#pragma unroll
    for (int m = 0; m < 16; ++m) H[(m<<13) + j] = h[m];  // transposed [16][8192]
}

// Per channel: filter time series -> packed FFT -> store (S~,D~) per bin pair.
__global__ __launch_bounds__(NT) void k_filter(const float* __restrict__ H, const float* __restrict__ t,
                                               const float* __restrict__ deltas, const float* __restrict__ W3,
                                               const float* __restrict__ b3, const float* __restrict__ ws,
                                               float* __restrict__ KfF) {
    __shared__ float2 lds[LSEQ];
    const int c = blockIdx.x;
    const int tid = threadIdx.x;
    const float2* tw   = (const float2*)(ws + OFF_TW);
    const float2* tw16 = (const float2*)(ws + OFF_TW16);
    float w3[16];
#pragma unroll
    for (int m = 0; m < 16; ++m) w3[m] = W3[m*NCH + c];
    const float b3c = b3[c];
    const float ad = fabsf(deltas[c]);
    for (int n = tid; n < 4096; n += NT) {
        float s0 = b3c, s1 = b3c;
#pragma unroll
        for (int m = 0; m < 16; ++m) {
            float2 hv = ((const float2*)(H + (m<<13)))[n];
            s0 += hv.x * w3[m]; s1 += hv.y * w3[m];
        }
        float2 tv = ((const float2*)t)[n];
        lds[IDX(n)] = make_float2(s0 * expf(-tv.x*ad), s1 * expf(-tv.y*ad));
    }
    for (int n = 4096 + tid; n < LSEQ; n += NT) lds[IDX(n)] = make_float2(0.f, 0.f);
    __syncthreads();
    fwd_fft(lds, tid, tw);

    float4* kf4 = (float4*)KfF + (size_t)c * 4096;
    const float sc = 1.0f / 32768.0f;
    for (int k = tid + 1; k < 4096; k += NT) {
        float2 V1 = lds[IDX(drev(k))];
        float2 V2 = lds[IDX(drev(LSEQ - k))];
        float2 E = make_float2(V1.x + V2.x, V1.y - V2.y);   // 2*E_k
        float2 O = make_float2(V1.y + V2.y, V2.x - V1.x);   // 2*O_k
        float2 D = cmul(tw16[k], O);
        kf4[k] = make_float4(E.x*sc, E.y*sc, D.x*sc, D.y*sc);
    }
    if (tid == 0) {
        float2 V0 = lds[0];
        float2 V = lds[IDX(1)];  // bin 4096
        kf4[0] = make_float4((V0.x + V0.y)/16384.f, (V0.x - V0.y)/16384.f,
                             V.x/8192.f, -V.y/8192.f);
    }
}

// Per row: pack x -> fwd FFT -> (unpack * K * repack, digit-reversed, swapped)
// -> DIT net -> unswap + x*bias -> store. Scale 1/8192 folded into Kf.
__global__ __launch_bounds__(NT) void k_main(const float* __restrict__ x, const float* __restrict__ ws,
                                             const float* __restrict__ KfF, const float* __restrict__ bias,
                                             float* __restrict__ out) {
    __shared__ float2 lds[LSEQ];
    const int bid = blockIdx.x;
    const int c = bid >> 3, bat = bid & 7;     // co-resident batches share Kf[c] in L2
    const int row = bat * NCH + c;
    const int tid = threadIdx.x;
    const float2* tw   = (const float2*)(ws + OFF_TW);
    const float2* tw16 = (const float2*)(ws + OFF_TW16);
    const float4* xrow4 = (const float4*)(x + (size_t)row * LSEQ);
    const float4* kf4 = (const float4*)KfF + (size_t)c * 4096;

    float4 xs[4];
#pragma unroll
    for (int j = 0; j < 4; ++j) {
        int i = tid + NT*j;
        float4 v = xrow4[i];
        xs[j] = v;
        lds[IDX(2*i)]   = make_float2(v.x, v.y);
        lds[IDX(2*i+1)] = make_float2(v.z, v.w);
    }
#pragma unroll
    for (int j = 0; j < 8; ++j) lds[IDX(4096 + tid + NT*j)] = make_float2(0.f, 0.f);
    __syncthreads();

    fwd_fft(lds, tid, tw);

    for (int k = tid + 1; k < 4096; k += NT) {
        int p1 = IDX(drev(k)), p2 = IDX(drev(LSEQ - k));
        float2 V1 = lds[p1], V2 = lds[p2];
        float4 kv = kf4[k];
        float2 W = tw16[k];
        float2 Eh = make_float2(V1.x + V2.x, V1.y - V2.y);   // V1 + conj(V2)
        float2 Oh = make_float2(V1.y + V2.y, V2.x - V1.x);   // -i(V1 - conj(V2))
        float2 S = make_float2(kv.x, kv.y);
        float a = W.x*kv.z, b = W.y*kv.w, cc = W.x*kv.w, dd = W.y*kv.z;
        float2 T  = make_float2(a - b, cc + dd);             // W*D
        float2 T2 = make_float2(a + b, cc - dd);             // conj(W)*D
        float2 Ep = cadd(cmul(Eh, S), cmul(Oh, T));
        float2 Op = cadd(cmul(Eh, T2), cmul(Oh, S));
        // v'[k] = Ep + i*Op, v'[8192-k] = conj(Ep) + i*conj(Op); store swapped (im,re)
        lds[p1] = make_float2(Ep.y + Op.x, Ep.x - Op.y);
        lds[p2] = make_float2(Op.x - Ep.y, Ep.x + Op.y);
    }
    if (tid == 0) {
        float2 V0 = lds[0];
        float4 kv = kf4[0];
        float U0 = V0.x + V0.y, UL = V0.x - V0.y;
        float re = U0*kv.x + UL*kv.y;
        float im = U0*kv.x - UL*kv.y;
        lds[0] = make_float2(im, re);                        // swapped
        int p = IDX(1);
        float2 V = lds[p];                                   // bin 4096
        float2 P = make_float2(V.x*kv.z + V.y*kv.w, V.x*kv.w - V.y*kv.z); // conj(V)*K
        lds[p] = make_float2(-P.y, P.x);                     // conj(P), swapped
    }
    __syncthreads();

    inv_fft(lds, tid, tw);

    const float bc = bias[c];
    float4* orow4 = (float4*)(out + (size_t)row * LSEQ);
#pragma unroll
    for (int j = 0; j < 4; ++j) {
        int i = tid + NT*j;
        float2 wA = lds[IDX(2*i)], wB = lds[IDX(2*i+1)];
        float4 xv = xs[j];
        orow4[i] = make_float4(wA.y + xv.x*bc, wA.x + xv.y*bc,
                               wB.y + xv.z*bc, wB.x + xv.w*bc);
    }
}

extern "C" void kernel_launch(void* const* d_in, const int* in_sizes, int n_in,
                              void* d_out, int out_size, void* d_ws, size_t ws_size,
                              hipStream_t stream) {
    const float* x      = (const float*)d_in[0];
    const float* z      = (const float*)d_in[2];
    const float* t      = (const float*)d_in[3];
    const float* deltas = (const float*)d_in[4];
    const float* freq   = (const float*)d_in[5];
    const float* W0     = (const float*)d_in[6];
    const float* b0     = (const float*)d_in[7];
    const float* W1     = (const float*)d_in[8];
    const float* b1     = (const float*)d_in[9];
    const float* W2     = (const float*)d_in[10];
    const float* b2     = (const float*)d_in[11];
    const float* W3     = (const float*)d_in[12];
    const float* b3     = (const float*)d_in[13];
    const float* bias   = (const float*)d_in[14];
    float* out = (float*)d_out;
    float* ws  = (float*)d_ws;
    float* H   = ws + OFF_H;
    float* Kf  = ws + OFF_KF;

    hipLaunchKernelGGL(k_init, dim3(17), dim3(256), 0, stream, ws);
    hipLaunchKernelGGL(k_mlp, dim3(16), dim3(512), 0, stream, z, freq, W0, b0, W1, b1, W2, b2, H);
    hipLaunchKernelGGL(k_filter, dim3(NCH), dim3(NT), 0, stream, H, t, deltas, W3, b3, ws, Kf);
    hipLaunchKernelGGL(k_main, dim3(NBATCH * NCH), dim3(NT), 0, stream, x, ws, Kf, bias, out);
}